// Round 1
// 99.972 us; speedup vs baseline: 1.0568x; 1.0568x over previous
//
#include <hip/hip_runtime.h>
#include <hip/hip_bf16.h>
#include <stdint.h>

#define BB 8
#define LL 2048
#define DD 64

typedef short bf16x8 __attribute__((ext_vector_type(8)));  // 8 bf16 (4 VGPRs)
typedef float f32x4 __attribute__((ext_vector_type(4)));
typedef unsigned short ushort_t;
typedef __attribute__((address_space(1))) const unsigned int gas_u32;
typedef __attribute__((address_space(3))) unsigned int las_u32;

// ---- helpers --------------------------------------------------------------
__device__ __forceinline__ unsigned pk2(float lo, float hi) {
    union { __hip_bfloat162 h; unsigned u; } c;
    c.h = __float22bfloat162_rn(make_float2(lo, hi));   // v_cvt_pk_bf16_f32
    return c.u;
}
__device__ __forceinline__ float4 ld4(const float* __restrict__ p) {
    return *reinterpret_cast<const float4*>(p);
}
__device__ __forceinline__ bf16x8 cvt8f(float4 a, float4 b) {
    union { bf16x8 v; unsigned u[4]; } r;
    r.u[0] = pk2(a.x, a.y); r.u[1] = pk2(a.z, a.w);
    r.u[2] = pk2(b.x, b.y); r.u[3] = pk2(b.z, b.w);
    return r.v;
}
// async global->LDS, 16B/lane; LDS dst = wave-uniform base + lane*16 (HW rule)
__device__ __forceinline__ void glds16(const void* g, void* lds_base_uniform) {
    __builtin_amdgcn_global_load_lds((gas_u32*)g, (las_u32*)lds_base_uniform, 16, 0, 0);
}
// fallback-kernel helpers (round-2 proven)
__device__ __forceinline__ unsigned f2bf_u(float f) {
    union { float f; unsigned u; } v; v.f = f;
    return (v.u + 0x8000u) >> 16;
}
__device__ __forceinline__ bf16x8 cvt8(const float* __restrict__ p) {
    float4 a = ld4(p), b = ld4(p + 4);
    union { bf16x8 v; unsigned u[4]; } r;
    r.u[0] = f2bf_u(a.x) | (f2bf_u(a.y) << 16);
    r.u[1] = f2bf_u(a.z) | (f2bf_u(a.w) << 16);
    r.u[2] = f2bf_u(b.x) | (f2bf_u(b.y) << 16);
    r.u[3] = f2bf_u(b.z) | (f2bf_u(b.w) << 16);
    return r.v;
}

// ---- prep (merged): K pack + V transpose in one dispatch ------------------
// blocks [0,512): K fp32 [b][k][d] -> bf16 same layout (8 elems/thread)
// blocks [512,768): V fp32 [b][k][d] -> bf16 transposed [b][d][k]
__global__ __launch_bounds__(256) void prep(const float* __restrict__ K,
                                            const float* __restrict__ V,
                                            ushort_t* __restrict__ Kb,
                                            ushort_t* __restrict__ VT) {
    __shared__ float t[64][65];
    if (blockIdx.x < 512) {
        size_t i = ((size_t)blockIdx.x * 256 + threadIdx.x) * 8;
        float4 a = ld4(K + i), b = ld4(K + i + 4);
        uint4 o = { pk2(a.x, a.y), pk2(a.z, a.w), pk2(b.x, b.y), pk2(b.z, b.w) };
        *reinterpret_cast<uint4*>(Kb + i) = o;
        return;
    }
    const int bx = blockIdx.x - 512;
    const int b  = bx >> 5;
    const int kt = (bx & 31) << 6;
    {
        const int r  = threadIdx.x >> 2;
        const int cq = (threadIdx.x & 3) << 4;
        const float* src = V + ((size_t)(b * LL + kt + r)) * DD + cq;
        #pragma unroll
        for (int i = 0; i < 4; ++i) {
            float4 v = ld4(src + 4 * i);
            t[r][cq + 4 * i + 0] = v.x; t[r][cq + 4 * i + 1] = v.y;
            t[r][cq + 4 * i + 2] = v.z; t[r][cq + 4 * i + 3] = v.w;
        }
    }
    __syncthreads();
    {
        const int d  = threadIdx.x >> 2;
        const int kq = (threadIdx.x & 3) << 4;
        ushort_t* dst = VT + ((size_t)(b * DD + d)) * LL + kt + kq;
        #pragma unroll
        for (int u = 0; u < 2; ++u) {
            uint4 o;
            o.x = pk2(t[kq + 8 * u + 0][d], t[kq + 8 * u + 1][d]);
            o.y = pk2(t[kq + 8 * u + 2][d], t[kq + 8 * u + 3][d]);
            o.z = pk2(t[kq + 8 * u + 4][d], t[kq + 8 * u + 5][d]);
            o.w = pk2(t[kq + 8 * u + 6][d], t[kq + 8 * u + 7][d]);
            *reinterpret_cast<uint4*>(dst + 8 * u) = o;
        }
    }
}

// ---- main attention kernel ------------------------------------------------
// 128-q tile + 4-way grid split-k (512 blocks, 8 waves, wave w owns q-subtile
// w over the block's full 512-k range). vs previous round:
//  * 3 LDS buffers, 2-deep prefetch, raw s_barrier + counted s_waitcnt
//    vmcnt(2): staging never drains to 0 inside the loop (T3/T4). Per-lane
//    vmem ops in the loop are EXACTLY the 2 STAGE loads/tile, so vmcnt(2)
//    == "tile it landed, tile it+1 may fly".
//  * P^T(C-layout)->P(A-layout) via permlane32_swap+permlane16_swap (T12)
//    instead of 16 ds_bpermute + 8 cndmask per tile.
//  * s_setprio(1) around MFMA clusters (T5).
//  * kmask staged as f32: one ds_read_b128/tt, no shift/cvt.
__global__ __launch_bounds__(512, 4) void attn8(
    const float* __restrict__ Q,
    const ushort_t* __restrict__ Kbf,
    const ushort_t* __restrict__ VTb,
    const int* __restrict__ kmask,
    float* __restrict__ Opart)
{
    const int tid  = threadIdx.x;
    const int wave = tid >> 6;         // q-subtile 0..7
    const int lane = tid & 63;
    const int ln   = lane & 15;
    const int quad = lane >> 4;

    const int bx    = blockIdx.x;
    const int ksp   = bx & 3;
    const int qt    = (bx >> 2) & 15;
    const int b     = bx >> 6;
    const int q0    = qt * 128;
    const int kbase = ksp * 512;

    __shared__ char  lds[3][16384];   // per buf: K 8KB [64k][128B] + V 8KB [64d][128B]
    __shared__ float kmf[512];        // kmask (block's k-range) as f32 0/1

    const char* Kg = (const char*)Kbf + (size_t)b * LL * DD * 2;
    const char* Vg = (const char*)VTb + (size_t)b * DD * LL * 2;
    const int gr = tid >> 3;                  // row 0..63 (k for K, d for V)
    const int gc = (tid & 7) ^ (gr & 7);      // swizzled source granule col

    #define STAGE(buf, k0)                                                     \
        do {                                                                   \
            glds16(Kg + (size_t)(kbase + (k0) + gr) * 128 + gc * 16,           \
                   &lds[buf][wave * 1024]);                                    \
            glds16(Vg + (size_t)gr * (LL * 2) + (kbase + (k0)) * 2 + gc * 16,  \
                   &lds[buf][8192 + wave * 1024]);                             \
        } while (0)

    // vmem issue order matters for the in-loop vmcnt counting: Q(4) and
    // kmask(1) go FIRST so their consuming waits (cvt / LDS store) leave the
    // 4 STAGE loads in flight.
    const float* qp = Q + ((size_t)(b * LL + q0 + 16 * wave + ln)) * DD + quad * 8;
    float4 qa = ld4(qp), qb = ld4(qp + 4), qc = ld4(qp + 32), qd = ld4(qp + 36);
    int4 km4 = {0, 0, 0, 0};
    if (tid < 128)
        km4 = *reinterpret_cast<const int4*>(kmask + b * LL + kbase + tid * 4);

    STAGE(0, 0);     // 2-deep prologue prefetch
    STAGE(1, 64);

    bf16x8 qf[2];   // q = q0+16*wave+ln, d = dh*32+quad*8+j
    qf[0] = cvt8f(qa, qb);
    qf[1] = cvt8f(qc, qd);
    if (tid < 128) {
        float4 f = { km4.x ? 1.f : 0.f, km4.y ? 1.f : 0.f,
                     km4.z ? 1.f : 0.f, km4.w ? 1.f : 0.f };
        *reinterpret_cast<float4*>(kmf + tid * 4) = f;
    }
    // publish kmf before the first raw barrier (raw s_barrier has no implicit
    // lgkm drain, unlike __syncthreads)
    asm volatile("s_waitcnt lgkmcnt(0)" ::: "memory");

    f32x4 Oacc[4] = {{0,0,0,0},{0,0,0,0},{0,0,0,0},{0,0,0,0}};
    float dsum = 0.f;
    const float EC = 0.125f * 1.44269504f;   // exp(x/8) = exp2(x*EC)

    // one k-tile: reads buf cb_, computes S->exp->permlane-transpose->PV
    auto tile = [&](int cb_, int it_) {
        const char* LK = lds[cb_];
        const char* LV = lds[cb_] + 8192;

        // K A-frags: rows 16tt+ln, d-half dh (swizzled granule col)
        bf16x8 kf[4][2];
        #pragma unroll
        for (int tt = 0; tt < 4; ++tt) {
            const int r = 16 * tt + ln;
            #pragma unroll
            for (int dh = 0; dh < 2; ++dh) {
                const int c = (dh * 4 + quad) ^ (ln & 7);
                kf[tt][dh] = *reinterpret_cast<const bf16x8*>(LK + r * 128 + c * 16);
            }
        }
        // V B-frags: d = db*16+ln, k-local = 32*kh + 8*quad + j (swizzled col)
        bf16x8 vf[2][4];
        #pragma unroll
        for (int kh = 0; kh < 2; ++kh) {
            const int c = (kh * 4 + quad) ^ (ln & 7);
            #pragma unroll
            for (int db = 0; db < 4; ++db) {
                const int d = db * 16 + ln;
                vf[kh][db] = *reinterpret_cast<const bf16x8*>(LV + d * 128 + c * 16);
            }
        }

        // S^T = K·Q^T; exp2*mask; pack  (lane holds P^T[k=16tt+4quad+r][q=ln])
        unsigned w[4][2];
        #pragma unroll
        for (int tt = 0; tt < 4; ++tt) {
            f32x4 acc = (f32x4){0.f, 0.f, 0.f, 0.f};
            __builtin_amdgcn_s_setprio(1);
            acc = __builtin_amdgcn_mfma_f32_16x16x32_bf16(kf[tt][0], qf[0], acc, 0, 0, 0);
            acc = __builtin_amdgcn_mfma_f32_16x16x32_bf16(kf[tt][1], qf[1], acc, 0, 0, 0);
            __builtin_amdgcn_s_setprio(0);
            float4 mu = *reinterpret_cast<const float4*>(
                kmf + it_ * 64 + 16 * tt + 4 * quad);
            float e0 = exp2f(acc[0] * EC) * mu.x;
            float e1 = exp2f(acc[1] * EC) * mu.y;
            float e2 = exp2f(acc[2] * EC) * mu.z;
            float e3 = exp2f(acc[3] * EC) * mu.w;
            dsum += (e0 + e1) + (e2 + e3);
            w[tt][0] = pk2(e0, e1);
            w[tt][1] = pk2(e2, e3);
        }
        // P^T(C-layout) -> P(A-layout) per 32-k group via permlane swaps.
        // Quad-chunk view (X = w[2g][r] = [x0 x1 x2 x3], Y = w[2g+1][r]):
        //   target pf.u[r]   = [x0 x2 y0 y2]   (old: shfl src0 + hi-select)
        //   target pf.u[r+2] = [x1 x3 y1 y3]   (old: shfl src1 + hi-select)
        // swap32(X,Y)  -> A={x0 x1 y0 y1}, B={x2 x3 y2 y3}
        // swap16(A,B)  -> {x0 x2 y0 y2}, {x1 x3 y1 y3}   -- exact match.
        #pragma unroll
        for (int g = 0; g < 2; ++g) {
            union { bf16x8 v; unsigned u[4]; } pf;
            #pragma unroll
            for (int r = 0; r < 2; ++r) {
                auto t32 = __builtin_amdgcn_permlane32_swap(
                    w[2 * g][r], w[2 * g + 1][r], false, false);
                auto t16 = __builtin_amdgcn_permlane16_swap(
                    t32[0], t32[1], false, false);
                pf.u[r]     = t16[0];
                pf.u[r + 2] = t16[1];
            }
            __builtin_amdgcn_s_setprio(1);
            #pragma unroll
            for (int db = 0; db < 4; ++db)
                Oacc[db] = __builtin_amdgcn_mfma_f32_16x16x32_bf16(
                    pf.v, vf[g][db], Oacc[db], 0, 0, 0);
            __builtin_amdgcn_s_setprio(0);
        }
    };

    // main loop: per-lane outstanding at loop top = stage(it)[2] + stage(it+1)[2]
    // -> vmcnt(2) == stage(it) landed, stage(it+1) still in flight.
    int cb = 0;
    for (int it = 0; it < 7; ++it) {
        asm volatile("s_waitcnt vmcnt(2)" ::: "memory");
        __builtin_amdgcn_s_barrier();
        asm volatile("" ::: "memory");     // keep STAGE below the barrier
        if (it < 6) {
            int sb = cb + 2; if (sb >= 3) sb -= 3;
            STAGE(sb, (it + 2) * 64);
        }
        tile(cb, it);
        cb = (cb == 2) ? 0 : cb + 1;
    }
    asm volatile("s_waitcnt vmcnt(0)" ::: "memory");
    __builtin_amdgcn_s_barrier();
    asm volatile("" ::: "memory");
    tile(cb, 7);
    #undef STAGE

    // den: reduce over quads (q = 16*wave + ln)
    {
        float v = dsum;
        v += __shfl_xor(v, 16);
        v += __shfl_xor(v, 32);
        dsum = v;
    }

    // write block partial: O rows q_local = 16*wave + quad*4 + r, col db*16+ln
    float* pb = Opart + (size_t)bx * 8320;   // 128*64 O + 128 den
    #pragma unroll
    for (int db = 0; db < 4; ++db)
        #pragma unroll
        for (int r = 0; r < 4; ++r)
            pb[(16 * wave + quad * 4 + r) * 64 + db * 16 + ln] = Oacc[db][r];
    if (quad == 0) pb[8192 + 16 * wave + ln] = dsum;
}

// ---- reduce: sum 4 k-split partials, normalize, mask, write Out -----------
// 256 blocks (was 128 -> only half the CUs); each block does 64 q rows.
__global__ __launch_bounds__(256) void reduce_norm(
    const float* __restrict__ Opart,
    const int* __restrict__ qmask,
    float* __restrict__ Out)
{
    const int rb   = blockIdx.x;       // 8b x 16qt x 2half = 256
    const int half = rb & 1;
    const int qt   = (rb >> 1) & 15;
    const int b    = rb >> 5;
    const int t    = threadIdx.x;
    const int q    = half * 64 + (t >> 2);   // 0..127
    const int d0   = (t & 3) * 16;

    const float* p0 = Opart + (size_t)((b * 16 + qt) * 4 + 0) * 8320;
    const float* p1 = p0 + 8320;
    const float* p2 = p1 + 8320;
    const float* p3 = p2 + 8320;

    float dn = p0[8192 + q] + p1[8192 + q] + p2[8192 + q] + p3[8192 + q];
    float sc = qmask[b * LL + qt * 128 + q] ? (1.0f / fmaxf(dn, 1.0f)) : 0.0f;

    const int off = q * 64 + d0;
    float* op = Out + ((size_t)(b * LL + qt * 128 + q)) * DD + d0;
    #pragma unroll
    for (int i = 0; i < 4; ++i) {
        f32x4 v = *reinterpret_cast<const f32x4*>(p0 + off + 4 * i)
                + *reinterpret_cast<const f32x4*>(p1 + off + 4 * i)
                + *reinterpret_cast<const f32x4*>(p2 + off + 4 * i)
                + *reinterpret_cast<const f32x4*>(p3 + off + 4 * i);
        *reinterpret_cast<f32x4*>(op + 4 * i) = v * sc;
    }
}

// ---- fallback (round-2 kernel, used only if ws too small) -----------------
__global__ __launch_bounds__(256, 4) void attn_mfma(
    const float* __restrict__ Q, const float* __restrict__ K,
    const float* __restrict__ V, const int* __restrict__ qmask,
    const int* __restrict__ kmask, float* __restrict__ Out)
{
    const int tid  = threadIdx.x;
    const int wave = tid >> 6;
    const int lane = tid & 63;
    const int n    = lane & 15;
    const int quad = lane >> 4;
    const int bx = blockIdx.x;
    const int b  = bx >> 7;
    const int q0 = (bx & 127) << 4;
    __shared__ float Pl[4][576];
    __shared__ float Opart2[4][16][68];
    __shared__ float Denp[4][16];
    const float* Qp = Q + ((size_t)(b * LL + q0 + n)) * DD + quad * 8;
    bf16x8 qf0 = cvt8(Qp);
    bf16x8 qf1 = cvt8(Qp + 32);
    const float* Kb = K + ((size_t)(b * LL) + n) * DD + quad * 8;
    const float* Vb = V + ((size_t)(b * LL) + quad * 8) * DD + n;
    const int* kmb = kmask + b * LL;
    f32x4 Oacc[4] = {{0,0,0,0},{0,0,0,0},{0,0,0,0},{0,0,0,0}};
    float den[4]  = {0.f, 0.f, 0.f, 0.f};
    float*       pw = &Pl[wave][144 * (n >> 3) + 36 * quad + (n & 7)];
    const float* pr = &Pl[wave][9 * lane];
    const int kbeg = wave * (LL / 4);
    const int kend = kbeg + (LL / 4);
    for (int k0 = kbeg; k0 < kend; k0 += 32) {
        const float* krow = Kb + (size_t)k0 * DD;
        bf16x8 kA0 = cvt8(krow);
        bf16x8 kA1 = cvt8(krow + 32);
        bf16x8 kB0 = cvt8(krow + 16 * DD);
        bf16x8 kB1 = cvt8(krow + 16 * DD + 32);
        f32x4 z = {0.f, 0.f, 0.f, 0.f};
        f32x4 S0 = __builtin_amdgcn_mfma_f32_16x16x32_bf16(qf0, kA0, z, 0, 0, 0);
        S0 = __builtin_amdgcn_mfma_f32_16x16x32_bf16(qf1, kA1, S0, 0, 0, 0);
        f32x4 S1 = __builtin_amdgcn_mfma_f32_16x16x32_bf16(qf0, kB0, z, 0, 0, 0);
        S1 = __builtin_amdgcn_mfma_f32_16x16x32_bf16(qf1, kB1, S1, 0, 0, 0);
        float km0 = (float)kmb[k0 + n];
        float km1 = (float)kmb[k0 + 16 + n];
        #pragma unroll
        for (int r = 0; r < 4; ++r) {
            float e0 = __expf(S0[r] * 0.125f) * km0;
            float e1 = __expf(S1[r] * 0.125f) * km1;
            den[r] += e0 + e1;
            pw[9 * r]       = e0;
            pw[288 + 9 * r] = e1;
        }
        __builtin_amdgcn_wave_barrier();
        float pv[8];
        #pragma unroll
        for (int j = 0; j < 8; ++j) pv[j] = pr[j];
        __builtin_amdgcn_wave_barrier();
        union { bf16x8 v; unsigned u[4]; } pf;
        #pragma unroll
        for (int j = 0; j < 4; ++j)
            pf.u[j] = f2bf_u(pv[2 * j]) | (f2bf_u(pv[2 * j + 1]) << 16);
        const float* vrow = Vb + (size_t)k0 * DD;
        #pragma unroll
        for (int db = 0; db < 4; ++db) {
            union { bf16x8 v; unsigned u[4]; } vfr;
            #pragma unroll
            for (int jj = 0; jj < 4; ++jj) {
                unsigned lo  = f2bf_u(vrow[(2 * jj) * DD + db * 16]);
                unsigned hi2 = f2bf_u(vrow[(2 * jj + 1) * DD + db * 16]);
                vfr.u[jj] = lo | (hi2 << 16);
            }
            Oacc[db] = __builtin_amdgcn_mfma_f32_16x16x32_bf16(pf.v, vfr.v, Oacc[db], 0, 0, 0);
        }
    }
    #pragma unroll
    for (int r = 0; r < 4; ++r) {
        float v = den[r];
        v += __shfl_xor(v, 1); v += __shfl_xor(v, 2);
        v += __shfl_xor(v, 4); v += __shfl_xor(v, 8);
        den[r] = v;
    }
    #pragma unroll
    for (int db = 0; db < 4; ++db)
        #pragma unroll
        for (int r = 0; r < 4; ++r)
            Opart2[wave][quad * 4 + r][db * 16 + n] = Oacc[db][r];
    if (n == 0) {
        #pragma unroll
        for (int r = 0; r < 4; ++r) Denp[wave][quad * 4 + r] = den[r];
    }
    __syncthreads();
    const int q  = tid >> 4;
    const int d0 = (tid & 15) * 4;
    f32x4 sum = *reinterpret_cast<const f32x4*>(&Opart2[0][q][d0]);
    sum += *reinterpret_cast<const f32x4*>(&Opart2[1][q][d0]);
    sum += *reinterpret_cast<const f32x4*>(&Opart2[2][q][d0]);
    sum += *reinterpret_cast<const f32x4*>(&Opart2[3][q][d0]);
    float dn  = Denp[0][q] + Denp[1][q] + Denp[2][q] + Denp[3][q];
    float inv = 1.0f / fmaxf(dn, 1.0f);
    float s   = qmask[b * LL + q0 + q] ? inv : 0.0f;
    f32x4 o   = sum * s;
    float* op = Out + ((size_t)(b * LL + q0 + q)) * DD + d0;
    *reinterpret_cast<f32x4*>(op) = o;
}

extern "C" void kernel_launch(void* const* d_in, const int* in_sizes, int n_in,
                              void* d_out, int out_size, void* d_ws, size_t ws_size,
                              hipStream_t stream) {
    (void)in_sizes; (void)n_in; (void)out_size;
    const float* Q  = (const float*)d_in[0];
    const float* K  = (const float*)d_in[1];
    const float* V  = (const float*)d_in[2];
    const int* qm   = (const int*)d_in[3];
    const int* km   = (const int*)d_in[4];
    float* Out      = (float*)d_out;

    const size_t elems   = (size_t)BB * LL * DD;             // 1,048,576
    const size_t part_off = 4u * 1024 * 1024;                // after Kbf+VTb
    const size_t ws_need  = part_off + (size_t)512 * 8320 * sizeof(float); // ~21.3 MB
    if (ws_size >= ws_need && d_ws != nullptr) {
        ushort_t* Kbf = (ushort_t*)d_ws;
        ushort_t* VTb = Kbf + elems;
        float* Opart  = (float*)((char*)d_ws + part_off);
        prep       <<<dim3(768), dim3(256), 0, stream>>>(K, V, Kbf, VTb);
        attn8      <<<dim3(512), dim3(512), 0, stream>>>(Q, Kbf, VTb, km, Opart);
        reduce_norm<<<dim3(256), dim3(256), 0, stream>>>(Opart, qm, Out);
    } else {
        attn_mfma<<<dim3(BB * (LL / 16)), dim3(256), 0, stream>>>(Q, K, V, qm, km, Out);
    }
}